// Round 1
// baseline (1064.403 us; speedup 1.0000x reference)
//
#include <hip/hip_runtime.h>
#include <hip/hip_bf16.h>
#include <math.h>

// GCN: h1 = norm-aggregate(x@W1)+b1 -> BN(eval)+ReLU -> h2 = norm-aggregate(h@W2)+b2
// logits = h2@lin2_w+lin2_b ; entropy-weighted softmax pooling ; out = graph@lin3_w+lin3_b
// N=100000, E=1600000, IN=H=64, OUT=32

#define F 64
#define OUTF 32
#define BN_INV 0.9999950000374997f  // rsqrt(1 + 1e-5)

__device__ __forceinline__ unsigned fenc(float f) {
    unsigned u = __float_as_uint(f);
    return (u & 0x80000000u) ? ~u : (u | 0x80000000u);
}
__device__ __forceinline__ float fdec(unsigned e) {
    return (e & 0x80000000u) ? __uint_as_float(e & 0x7fffffffu) : __uint_as_float(~e);
}

// red layout (floats unless noted): [0..31] acc_c, [32] esum, [33] min-enc (uint), [34] max-enc (uint)
__global__ void k_init(float* __restrict__ deg, float* __restrict__ red, int N) {
    int i = blockIdx.x * blockDim.x + threadIdx.x;
    if (i < N) deg[i] = 0.0f;
    if (i < 33) red[i] = 0.0f;
    if (i == 33) ((unsigned*)red)[33] = 0xFFFFFFFFu;
    if (i == 34) ((unsigned*)red)[34] = 0u;
}

__global__ void k_deg(const int* __restrict__ dst, float* __restrict__ deg, int E) {
    int e = blockIdx.x * blockDim.x + threadIdx.x;
    if (e < E) unsafeAtomicAdd(&deg[dst[e]], 1.0f);
}

__global__ void k_dinv(float* __restrict__ deg, int N) {
    int i = blockIdx.x * blockDim.x + threadIdx.x;
    if (i < N) deg[i] = rsqrtf(deg[i] + 1.0f);  // +1 self-loop; deg>=1 always
}

// out[i,c] = h[i,c] * dinv[i]^2   (self-loop term, also zero-initializes accumulator)
__global__ void k_selfloop(const float* __restrict__ h, const float* __restrict__ dinv,
                           float* __restrict__ out, long long total) {
    long long idx = (long long)blockIdx.x * blockDim.x + threadIdx.x;
    if (idx < total) {
        float di = dinv[idx >> 6];
        out[idx] = h[idx] * di * di;
    }
}

// one 64-lane group per edge: out[dst, c] += h[src, c] * dinv[src]*dinv[dst]
__global__ __launch_bounds__(256) void k_edges(const int* __restrict__ src, const int* __restrict__ dst,
                                               const float* __restrict__ dinv, const float* __restrict__ h,
                                               float* __restrict__ out, int E) {
    int e = (int)((blockIdx.x * 256 + threadIdx.x) >> 6);
    int c = threadIdx.x & 63;
    if (e < E) {
        int s = src[e], d = dst[e];
        float nrm = dinv[s] * dinv[d];
        unsafeAtomicAdd(&out[(long long)d * F + c], h[(long long)s * F + c] * nrm);
    }
}

// MODE: 0 = plain, 1 = input gets bias+BN+ReLU (b_in,gamma,beta)
template <int MODE>
__global__ __launch_bounds__(256) void k_gemm64(const float* __restrict__ x, const float* __restrict__ W,
                                                const float* __restrict__ b_in, const float* __restrict__ gamma,
                                                const float* __restrict__ beta, float* __restrict__ out, int N) {
    constexpr int RPI = 4;  // rows per iteration (256 threads / 64 cols)
    __shared__ float Wl[F * F];
    __shared__ float xs[RPI][F + 1];
    int tid = threadIdx.x;
    for (int idx = tid; idx < F * F; idx += 256) Wl[idx] = W[idx];
    int c = tid & 63;
    int rsub = tid >> 6;
    for (int row0 = blockIdx.x * RPI; row0 < N; row0 += gridDim.x * RPI) {
        __syncthreads();
        {
            int r = row0 + (tid >> 6);
            int k = tid & 63;
            float v = (r < N) ? x[(long long)r * F + k] : 0.0f;
            if (MODE == 1) v = fmaxf(gamma[k] * ((v + b_in[k]) * BN_INV) + beta[k], 0.0f);
            xs[tid >> 6][k] = v;
        }
        __syncthreads();
        int r = row0 + rsub;
        if (r < N) {
            float acc = 0.0f;
#pragma unroll
            for (int k = 0; k < F; k++) acc += xs[rsub][k] * Wl[k * F + c];
            out[(long long)r * F + c] = acc;
        }
    }
}

// logits = (x + b2) @ l2w + l2b ; fused per-row softmax-entropy -> wraw ; block min/max -> red
__global__ __launch_bounds__(256) void k_logits(const float* __restrict__ x, const float* __restrict__ W,
                                                const float* __restrict__ b_in, const float* __restrict__ b_out,
                                                float* __restrict__ logits, float* __restrict__ wraw,
                                                unsigned* __restrict__ redmm, int N) {
    constexpr int RPI = 8;  // 256 threads / 32 cols
    __shared__ float Wl[F * OUTF];
    __shared__ float xs[RPI][F + 1];
    __shared__ float smn[256], smx[256];
    int tid = threadIdx.x;
    for (int idx = tid; idx < F * OUTF; idx += 256) Wl[idx] = W[idx];
    int c = tid & 31;
    int rsub = tid >> 5;
    float mn = INFINITY, mx = -INFINITY;
    for (int row0 = blockIdx.x * RPI; row0 < N; row0 += gridDim.x * RPI) {
        __syncthreads();
        for (int idx = tid; idx < RPI * F; idx += 256) {
            int r = row0 + (idx >> 6);
            int k = idx & 63;
            xs[idx >> 6][k] = (r < N) ? x[(long long)r * F + k] + b_in[k] : 0.0f;
        }
        __syncthreads();
        int r = row0 + rsub;
        if (r < N) {
            float acc = b_out[c];
#pragma unroll
            for (int k = 0; k < F; k++) acc += xs[rsub][k] * Wl[k * OUTF + c];
            logits[(long long)r * OUTF + c] = acc;
            // softmax + entropy across the 32 lanes of this row
            float m = acc;
            for (int o = 16; o > 0; o >>= 1) m = fmaxf(m, __shfl_xor(m, o, 32));
            float p = expf(acc - m);
            float s = p;
            for (int o = 16; o > 0; o >>= 1) s += __shfl_xor(s, o, 32);
            float t = p / s;
            float term = t * logf(t + 1e-9f);
            float ent = term;
            for (int o = 16; o > 0; o >>= 1) ent += __shfl_xor(ent, o, 32);
            ent = -ent;
            float w = 1.0f / (ent + 1e-10f);
            if (c == 0) {
                wraw[r] = w;
                mn = fminf(mn, w);
                mx = fmaxf(mx, w);
            }
        }
    }
    smn[tid] = mn;
    smx[tid] = mx;
    __syncthreads();
    if (tid == 0) {
        float a = INFINITY, b = -INFINITY;
        for (int i = 0; i < 256; i++) {
            a = fminf(a, smn[i]);
            b = fmaxf(b, smx[i]);
        }
        atomicMin(&redmm[33], fenc(a));
        atomicMax(&redmm[34], fenc(b));
    }
}

// acc[c] += sum_i exp((w_i - mn)/(mx - mn)) * logits[i,c] ; esum += sum_i exp(...)
__global__ __launch_bounds__(256) void k_weight(const float* __restrict__ logits, const float* __restrict__ wraw,
                                                float* __restrict__ red, int N) {
    const unsigned* mm = (const unsigned*)red;
    float mn = fdec(mm[33]), mx = fdec(mm[34]);
    float inv = 1.0f / (mx - mn);
    int c = threadIdx.x & 31;
    int g = threadIdx.x >> 5;  // 8 row-groups
    float acc = 0.0f, es = 0.0f;
    for (int r = blockIdx.x * 8 + g; r < N; r += gridDim.x * 8) {
        float e = expf((wraw[r] - mn) * inv);
        acc += e * logits[(long long)r * OUTF + c];
        if (c == 0) es += e;
    }
    __shared__ float sa[8][OUTF];
    __shared__ float se[8];
    sa[g][c] = acc;
    if (c == 0) se[g] = es;
    __syncthreads();
    if (g == 0) {
        float t = sa[0][c];
#pragma unroll
        for (int i = 1; i < 8; i++) t += sa[i][c];
        unsafeAtomicAdd(&red[c], t);
        if (c == 0) {
            float u = 0.0f;
#pragma unroll
            for (int i = 0; i < 8; i++) u += se[i];
            unsafeAtomicAdd(&red[32], u);
        }
    }
}

// out[j] = lin3_b[j] + sum_c (acc[c]/esum) * lin3_w[c,j]
__global__ void k_final(const float* __restrict__ red, const float* __restrict__ w3,
                        const float* __restrict__ b3, float* __restrict__ out) {
    int j = threadIdx.x;  // 64 threads
    float s = red[32];
    float o = b3[j];
#pragma unroll
    for (int cc = 0; cc < OUTF; cc++) o += (red[cc] / s) * w3[cc * F + j];
    out[j] = o;
}

extern "C" void kernel_launch(void* const* d_in, const int* in_sizes, int n_in,
                              void* d_out, int out_size, void* d_ws, size_t ws_size,
                              hipStream_t stream) {
    const float* x     = (const float*)d_in[0];
    const int*   ei    = (const int*)d_in[1];
    const float* W1    = (const float*)d_in[2];
    const float* b1    = (const float*)d_in[3];
    const float* gamma = (const float*)d_in[4];
    const float* beta  = (const float*)d_in[5];
    const float* W2    = (const float*)d_in[6];
    const float* b2    = (const float*)d_in[7];
    const float* l2w   = (const float*)d_in[8];
    const float* l2b   = (const float*)d_in[9];
    const float* l3w   = (const float*)d_in[10];
    const float* l3b   = (const float*)d_in[11];

    int N = in_sizes[0] / F;
    int E = in_sizes[1] / 2;
    const int* src = ei;
    const int* dst = ei + E;

    float* ws     = (float*)d_ws;
    float* deg    = ws;                           // N   (becomes dinv)
    float* bufA   = deg + N;                      // N*64
    float* bufB   = bufA + (size_t)N * F;         // N*64
    float* logits = bufB + (size_t)N * F;         // N*32
    float* wraw   = logits + (size_t)N * OUTF;    // N
    float* red    = wraw + N;                     // 64 slots

    long long totF = (long long)N * F;
    int gElem = (int)((totF + 255) / 256);

    k_init<<<(N + 255) / 256, 256, 0, stream>>>(deg, red, N);
    k_deg<<<(E + 255) / 256, 256, 0, stream>>>(dst, deg, E);
    k_dinv<<<(N + 255) / 256, 256, 0, stream>>>(deg, N);

    // conv1: h = x@W1 ; agg ; (+b1, BN, ReLU fused into next GEMM's input)
    k_gemm64<0><<<2048, 256, 0, stream>>>(x, W1, nullptr, nullptr, nullptr, bufA, N);
    k_selfloop<<<gElem, 256, 0, stream>>>(bufA, deg, bufB, totF);
    k_edges<<<(E + 3) / 4, 256, 0, stream>>>(src, dst, deg, bufA, bufB, E);

    // conv2: h = f(agg1)@W2 ; agg ; (+b2 fused into logits GEMM input)
    k_gemm64<1><<<2048, 256, 0, stream>>>(bufB, W2, b1, gamma, beta, bufA, N);
    k_selfloop<<<gElem, 256, 0, stream>>>(bufA, deg, bufB, totF);
    k_edges<<<(E + 3) / 4, 256, 0, stream>>>(src, dst, deg, bufA, bufB, E);

    // head
    k_logits<<<2048, 256, 0, stream>>>(bufB, l2w, b2, l2b, logits, wraw, (unsigned*)red, N);
    k_weight<<<1024, 256, 0, stream>>>(logits, wraw, red, N);
    k_final<<<1, 64, 0, stream>>>(red, l3w, l3b, (float*)d_out);
}

// Round 2
// 661.849 us; speedup vs baseline: 1.6082x; 1.6082x over previous
//
#include <hip/hip_runtime.h>
#include <hip/hip_bf16.h>
#include <math.h>

// GCN via CSR-gather (no 256B scatter atomics):
//   CSR build (deg -> scan -> scatter) once, reused by both convs.
//   conv = dinv[i]*(sum_{s in N(i)} xp[s] + xp[i]) with xp pre-scaled by dinv,
//   GEMM fused into aggregation epilogue via shuffle-broadcast (A(XW)=(AX)W).
//   conv2 epilogue uses precomputed W2@lin2_w so logits+softmax+entropy fuse in.

#define F 64
#define OUTF 32
#define BN_INV 0.9999950000374997f  // rsqrt(1 + 1e-5)

__device__ __forceinline__ unsigned fenc(float f) {
    unsigned u = __float_as_uint(f);
    return (u & 0x80000000u) ? ~u : (u | 0x80000000u);
}
__device__ __forceinline__ float fdec(unsigned e) {
    return (e & 0x80000000u) ? __uint_as_float(e & 0x7fffffffu) : __uint_as_float(~e);
}

// red layout: [0..31] acc_c, [32] esum, [33] min-enc(uint), [34] max-enc(uint)
__global__ void k_init(int* __restrict__ deg, float* __restrict__ red, int N) {
    int i = blockIdx.x * blockDim.x + threadIdx.x;
    if (i < N) deg[i] = 0;
    if (i < 33) red[i] = 0.0f;
    if (i == 33) ((unsigned*)red)[33] = 0xFFFFFFFFu;
    if (i == 34) ((unsigned*)red)[34] = 0u;
}

__global__ void k_deg(const int* __restrict__ dst, int* __restrict__ deg, int E) {
    int e = blockIdx.x * blockDim.x + threadIdx.x;
    if (e < E) atomicAdd(&deg[dst[e]], 1);
}

__global__ void k_scan1(const int* __restrict__ deg, int* __restrict__ rowptr,
                        int* __restrict__ bsum, int N) {
    __shared__ int s[256];
    int t = threadIdx.x;
    int i = blockIdx.x * 256 + t;
    int v = (i < N) ? deg[i] : 0;
    s[t] = v;
    __syncthreads();
    for (int off = 1; off < 256; off <<= 1) {
        int u = (t >= off) ? s[t - off] : 0;
        __syncthreads();
        s[t] += u;
        __syncthreads();
    }
    if (i < N) rowptr[i] = s[t] - v;  // exclusive within block
    if (t == 255) bsum[blockIdx.x] = s[255];
}

__global__ void k_scan2(int* __restrict__ bsum, int NB) {
    __shared__ int s[512];
    int t = threadIdx.x;
    int v = (t < NB) ? bsum[t] : 0;
    s[t] = v;
    __syncthreads();
    for (int off = 1; off < 512; off <<= 1) {
        int u = (t >= off) ? s[t - off] : 0;
        __syncthreads();
        s[t] += u;
        __syncthreads();
    }
    if (t < NB) bsum[t] = s[t] - v;  // exclusive
}

__global__ void k_scan3(const int* __restrict__ deg, int* __restrict__ rowptr,
                        int* __restrict__ cursor, float* __restrict__ dinv,
                        const int* __restrict__ bsum, int N, int E) {
    int i = blockIdx.x * blockDim.x + threadIdx.x;
    if (i < N) {
        int r = rowptr[i] + bsum[i >> 8];
        rowptr[i] = r;
        cursor[i] = r;
        dinv[i] = rsqrtf((float)deg[i] + 1.0f);
    }
    if (i == 0) rowptr[N] = E;
}

__global__ void k_scatter(const int* __restrict__ src, const int* __restrict__ dst,
                          int* __restrict__ cursor, int* __restrict__ eidx, int E) {
    int e = blockIdx.x * blockDim.x + threadIdx.x;
    if (e < E) {
        int p = atomicAdd(&cursor[dst[e]], 1);
        eidx[p] = src[e];
    }
}

__global__ void k_prescale(const float* __restrict__ x, const float* __restrict__ dinv,
                           float* __restrict__ xp, long long total) {
    long long idx = (long long)blockIdx.x * blockDim.x + threadIdx.x;
    if (idx < total) xp[idx] = x[idx] * dinv[idx >> 6];
}

// w2l2 = W2 @ lin2_w  [64x32]; b2l2 = b2 @ lin2_w + lin2_b  [32]
__global__ void k_fuse(const float* __restrict__ W2, const float* __restrict__ b2,
                       const float* __restrict__ l2w, const float* __restrict__ l2b,
                       float* __restrict__ w2l2, float* __restrict__ b2l2) {
    int t = blockIdx.x * blockDim.x + threadIdx.x;  // 2048 threads
    int k = t >> 5, cc = t & 31;
    float o = 0.0f;
    for (int j = 0; j < F; j++) o += W2[k * F + j] * l2w[j * OUTF + cc];
    w2l2[k * OUTF + cc] = o;
    if (t < OUTF) {
        float b = l2b[t];
        for (int j = 0; j < F; j++) b += b2[j] * l2w[j * OUTF + t];
        b2l2[t] = b;
    }
}

__device__ __forceinline__ float gather_row(const float* __restrict__ xp,
                                            const int* __restrict__ eidx,
                                            int beg, int dcnt, int c, float self) {
    float acc = self;
    for (int base = 0; base < dcnt; base += 64) {
        int j = base + c;
        int ss = (j < dcnt) ? eidx[beg + j] : 0;
        int cnt = min(64, dcnt - base);
        int k = 0;
        for (; k + 4 <= cnt; k += 4) {
            int s0 = __shfl(ss, k, 64), s1 = __shfl(ss, k + 1, 64);
            int s2 = __shfl(ss, k + 2, 64), s3 = __shfl(ss, k + 3, 64);
            float a0 = xp[(long long)s0 * F + c];
            float a1 = xp[(long long)s1 * F + c];
            float a2 = xp[(long long)s2 * F + c];
            float a3 = xp[(long long)s3 * F + c];
            acc += a0; acc += a1; acc += a2; acc += a3;
        }
        for (; k < cnt; k++) {
            int s = __shfl(ss, k, 64);
            acc += xp[(long long)s * F + c];
        }
    }
    return acc;
}

// conv1 fused: t1 = A_hat x ; h1s = ReLU(gamma*((t1@W1+b1)*BN_INV)+beta) * dinv[i]
__global__ __launch_bounds__(256) void k_conv1(const float* __restrict__ xp, const int* __restrict__ rowptr,
                                               const int* __restrict__ eidx, const float* __restrict__ dinv,
                                               const float* __restrict__ W1, const float* __restrict__ b1,
                                               const float* __restrict__ gamma, const float* __restrict__ beta,
                                               float* __restrict__ h1s, int N) {
    __shared__ float Wl[F * F];
    int tid = threadIdx.x;
    for (int idx = tid; idx < F * F; idx += 256) Wl[idx] = W1[idx];
    __syncthreads();
    int wave = tid >> 6, c = tid & 63;
    float b1c = b1[c], gc = gamma[c], bc = beta[c];
    for (int i = blockIdx.x * 4 + wave; i < N; i += gridDim.x * 4) {
        float di = dinv[i];
        int beg = rowptr[i], dcnt = rowptr[i + 1] - beg;
        float acc = gather_row(xp, eidx, beg, dcnt, c, xp[(long long)i * F + c]);
        acc *= di;  // t1[i, c], lane c holds channel c
        float o = 0.0f;
#pragma unroll
        for (int k = 0; k < F; k++) o += __shfl(acc, k, 64) * Wl[k * F + c];
        o = fmaxf(gc * ((o + b1c) * BN_INV) + bc, 0.0f) * di;
        h1s[(long long)i * F + c] = o;
    }
}

// conv2 fused: t2 = A_hat h1 ; logits = t2@w2l2 + b2l2 ; softmax+entropy -> wraw, block min/max
__global__ __launch_bounds__(256) void k_conv2(const float* __restrict__ h1s, const int* __restrict__ rowptr,
                                               const int* __restrict__ eidx, const float* __restrict__ dinv,
                                               const float* __restrict__ w2l2, const float* __restrict__ b2l2,
                                               float* __restrict__ logits, float* __restrict__ wraw,
                                               unsigned* __restrict__ redmm, int N) {
    __shared__ float Wl[F * OUTF];
    __shared__ float smn[256], smx[256];
    int tid = threadIdx.x;
    for (int idx = tid; idx < F * OUTF; idx += 256) Wl[idx] = w2l2[idx];
    __syncthreads();
    int wave = tid >> 6, c = tid & 63, cc = c & 31;
    float bcc = b2l2[cc];
    float mn = INFINITY, mx = -INFINITY;
    for (int i = blockIdx.x * 4 + wave; i < N; i += gridDim.x * 4) {
        float di = dinv[i];
        int beg = rowptr[i], dcnt = rowptr[i + 1] - beg;
        float acc = gather_row(h1s, eidx, beg, dcnt, c, h1s[(long long)i * F + c]);
        acc *= di;  // t2[i, c]
        float o = bcc;
#pragma unroll
        for (int k = 0; k < F; k++) o += __shfl(acc, k, 64) * Wl[k * OUTF + cc];
        // softmax + entropy across 32 lanes (upper half duplicates lower)
        float m = o;
        for (int off = 16; off > 0; off >>= 1) m = fmaxf(m, __shfl_xor(m, off, 32));
        float p = expf(o - m);
        float sum = p;
        for (int off = 16; off > 0; off >>= 1) sum += __shfl_xor(sum, off, 32);
        float t = p / sum;
        float ent = t * logf(t + 1e-9f);
        for (int off = 16; off > 0; off >>= 1) ent += __shfl_xor(ent, off, 32);
        ent = -ent;
        float w = 1.0f / (ent + 1e-10f);
        if (c < 32) logits[(long long)i * OUTF + c] = o;
        if (c == 0) {
            wraw[i] = w;
            mn = fminf(mn, w);
            mx = fmaxf(mx, w);
        }
    }
    smn[tid] = mn;
    smx[tid] = mx;
    __syncthreads();
    if (tid == 0) {
        float a = INFINITY, b = -INFINITY;
        for (int i2 = 0; i2 < 256; i2++) {
            a = fminf(a, smn[i2]);
            b = fmaxf(b, smx[i2]);
        }
        atomicMin(&redmm[33], fenc(a));
        atomicMax(&redmm[34], fenc(b));
    }
}

__global__ __launch_bounds__(256) void k_weight(const float* __restrict__ logits, const float* __restrict__ wraw,
                                                float* __restrict__ red, int N) {
    const unsigned* mm = (const unsigned*)red;
    float mn = fdec(mm[33]), mx = fdec(mm[34]);
    float inv = 1.0f / (mx - mn);
    int c = threadIdx.x & 31;
    int g = threadIdx.x >> 5;  // 8 row-groups
    float acc = 0.0f, es = 0.0f;
    for (int r = blockIdx.x * 8 + g; r < N; r += gridDim.x * 8) {
        float e = expf((wraw[r] - mn) * inv);
        acc += e * logits[(long long)r * OUTF + c];
        if (c == 0) es += e;
    }
    __shared__ float sa[8][OUTF];
    __shared__ float se[8];
    sa[g][c] = acc;
    if (c == 0) se[g] = es;
    __syncthreads();
    if (g == 0) {
        float t = sa[0][c];
#pragma unroll
        for (int i = 1; i < 8; i++) t += sa[i][c];
        unsafeAtomicAdd(&red[c], t);
        if (c == 0) {
            float u = 0.0f;
#pragma unroll
            for (int i = 0; i < 8; i++) u += se[i];
            unsafeAtomicAdd(&red[32], u);
        }
    }
}

__global__ void k_final(const float* __restrict__ red, const float* __restrict__ w3,
                        const float* __restrict__ b3, float* __restrict__ out) {
    int j = threadIdx.x;  // 64 threads
    float s = red[32];
    float o = b3[j];
#pragma unroll
    for (int cc = 0; cc < OUTF; cc++) o += (red[cc] / s) * w3[cc * F + j];
    out[j] = o;
}

extern "C" void kernel_launch(void* const* d_in, const int* in_sizes, int n_in,
                              void* d_out, int out_size, void* d_ws, size_t ws_size,
                              hipStream_t stream) {
    const float* x     = (const float*)d_in[0];
    const int*   ei    = (const int*)d_in[1];
    const float* W1    = (const float*)d_in[2];
    const float* b1    = (const float*)d_in[3];
    const float* gamma = (const float*)d_in[4];
    const float* beta  = (const float*)d_in[5];
    const float* W2    = (const float*)d_in[6];
    const float* b2    = (const float*)d_in[7];
    const float* l2w   = (const float*)d_in[8];
    const float* l2b   = (const float*)d_in[9];
    const float* l3w   = (const float*)d_in[10];
    const float* l3b   = (const float*)d_in[11];

    int N = in_sizes[0] / F;
    int E = in_sizes[1] / 2;
    const int* src = ei;
    const int* dst = ei + E;
    int NB = (N + 255) / 256;  // scan blocks (391 <= 512)

    // workspace layout
    int* deg    = (int*)d_ws;                  // N
    int* rowptr = deg + N;                     // N+1
    int* cursor = rowptr + N + 1;              // N
    int* bsum   = cursor + N;                  // 512
    int* eidx   = bsum + 512;                  // E
    float* dinv = (float*)(eidx + E);          // N
    float* red  = dinv + N;                    // 64
    float* w2l2 = red + 64;                    // 2048
    float* b2l2 = w2l2 + F * OUTF;             // 32
    float* h1s  = b2l2 + OUTF;                 // N*64
    float* xp   = h1s + (size_t)N * F;         // N*64  (aliased by logits/wraw after conv1)
    float* logits = xp;                        // N*32  (alias — xp dead after conv1)
    float* wraw   = xp + (size_t)N * OUTF;     // N

    long long totF = (long long)N * F;
    int gElem = (int)((totF + 255) / 256);

    // CSR build
    k_init<<<NB, 256, 0, stream>>>(deg, red, N);
    k_deg<<<(E + 255) / 256, 256, 0, stream>>>(dst, deg, E);
    k_scan1<<<NB, 256, 0, stream>>>(deg, rowptr, bsum, N);
    k_scan2<<<1, 512, 0, stream>>>(bsum, NB);
    k_scan3<<<NB, 256, 0, stream>>>(deg, rowptr, cursor, dinv, bsum, N, E);
    k_scatter<<<(E + 255) / 256, 256, 0, stream>>>(src, dst, cursor, eidx, E);

    // head weight fusion (independent)
    k_fuse<<<8, 256, 0, stream>>>(W2, b2, l2w, l2b, w2l2, b2l2);

    // conv1 (gather + GEMM + bias/BN/ReLU + pre-scale by dinv)
    k_prescale<<<gElem, 256, 0, stream>>>(x, dinv, xp, totF);
    k_conv1<<<2048, 256, 0, stream>>>(xp, rowptr, eidx, dinv, W1, b1, gamma, beta, h1s, N);

    // conv2 (gather + fused lin2 GEMM + softmax/entropy)
    k_conv2<<<2048, 256, 0, stream>>>(h1s, rowptr, eidx, dinv, w2l2, b2l2, logits, wraw, (unsigned*)red, N);

    // pooling head
    k_weight<<<1024, 256, 0, stream>>>(logits, wraw, red, N);
    k_final<<<1, 64, 0, stream>>>(red, l3w, l3b, (float*)d_out);
}

// Round 3
// 535.429 us; speedup vs baseline: 1.9879x; 1.2361x over previous
//
#include <hip/hip_runtime.h>
#include <hip/hip_bf16.h>
#include <math.h>

// GCN via CSR-gather. Convs: one wave per node; gather neighbors (coalesced 256B
// rows), GEMM fused in epilogue with W columns in VGPRs + per-wave LDS broadcast
// of the aggregated vector (1 ds_write + 16 ds_read_b128 per row, vs 128 LGKM
// ops/row in round 2). CSR scan collapsed to one block-scan + atomic-base kernel.

#define F 64
#define OUTF 32
#define BN_INV 0.9999950000374997f  // rsqrt(1 + 1e-5)

__device__ __forceinline__ unsigned fenc(float f) {
    unsigned u = __float_as_uint(f);
    return (u & 0x80000000u) ? ~u : (u | 0x80000000u);
}
__device__ __forceinline__ float fdec(unsigned e) {
    return (e & 0x80000000u) ? __uint_as_float(e & 0x7fffffffu) : __uint_as_float(~e);
}

// red layout: [0..31] acc_c, [32] esum, [33] min-enc(uint), [34] max-enc(uint), [35] gcount(int)

// w2l2 = W2 @ lin2_w [64x32]; b2l2 = b2 @ lin2_w + lin2_b [32]; also inits red
__global__ void k_fuse(const float* __restrict__ W2, const float* __restrict__ b2,
                       const float* __restrict__ l2w, const float* __restrict__ l2b,
                       float* __restrict__ w2l2, float* __restrict__ b2l2, float* __restrict__ red) {
    int t = blockIdx.x * blockDim.x + threadIdx.x;  // 2048 threads
    int k = t >> 5, cc = t & 31;
    float o = 0.0f;
    for (int j = 0; j < F; j++) o += W2[k * F + j] * l2w[j * OUTF + cc];
    w2l2[k * OUTF + cc] = o;
    if (t < OUTF) {
        float b = l2b[t];
        for (int j = 0; j < F; j++) b += b2[j] * l2w[j * OUTF + t];
        b2l2[t] = b;
    }
    if (t < 33) red[t] = 0.0f;
    if (t == 33) ((unsigned*)red)[33] = 0xFFFFFFFFu;
    if (t == 34) ((unsigned*)red)[34] = 0u;
    if (t == 35) ((int*)red)[35] = 0;
}

__global__ void k_deg4(const int4* __restrict__ dst4, int* __restrict__ deg, int E4) {
    int e = blockIdx.x * blockDim.x + threadIdx.x;
    if (e < E4) {
        int4 d = dst4[e];
        atomicAdd(&deg[d.x], 1);
        atomicAdd(&deg[d.y], 1);
        atomicAdd(&deg[d.z], 1);
        atomicAdd(&deg[d.w], 1);
    }
}
__global__ void k_deg1(const int* __restrict__ dst, int* __restrict__ deg, int E) {
    int e = blockIdx.x * blockDim.x + threadIdx.x;
    if (e < E) atomicAdd(&deg[dst[e]], 1);
}

// block-scan deg; block base from atomic counter (segment order arbitrary — valid CSR)
__global__ void k_rowptr(const int* __restrict__ deg, int* __restrict__ rowptr, int* __restrict__ cursor,
                         float* __restrict__ dinv, int* __restrict__ gcount, int N) {
    __shared__ int s[256];
    __shared__ int base_s;
    int t = threadIdx.x, i = blockIdx.x * 256 + t;
    int v = (i < N) ? deg[i] : 0;
    s[t] = v;
    __syncthreads();
    for (int off = 1; off < 256; off <<= 1) {
        int u = (t >= off) ? s[t - off] : 0;
        __syncthreads();
        s[t] += u;
        __syncthreads();
    }
    int incl = s[t];
    if (t == 255) base_s = atomicAdd(gcount, incl);
    __syncthreads();
    if (i < N) {
        int r = base_s + incl - v;
        rowptr[i] = r;
        cursor[i] = r;
        dinv[i] = rsqrtf((float)v + 1.0f);
    }
}

__global__ void k_scatter4(const int4* __restrict__ src4, const int4* __restrict__ dst4,
                           int* __restrict__ cursor, int* __restrict__ eidx, int E4) {
    int e = blockIdx.x * blockDim.x + threadIdx.x;
    if (e < E4) {
        int4 s = src4[e], d = dst4[e];
        eidx[atomicAdd(&cursor[d.x], 1)] = s.x;
        eidx[atomicAdd(&cursor[d.y], 1)] = s.y;
        eidx[atomicAdd(&cursor[d.z], 1)] = s.z;
        eidx[atomicAdd(&cursor[d.w], 1)] = s.w;
    }
}
__global__ void k_scatter1(const int* __restrict__ src, const int* __restrict__ dst,
                           int* __restrict__ cursor, int* __restrict__ eidx, int E) {
    int e = blockIdx.x * blockDim.x + threadIdx.x;
    if (e < E) {
        int p = atomicAdd(&cursor[dst[e]], 1);
        eidx[p] = src[e];
    }
}

__global__ void k_prescale4(const float4* __restrict__ x4, const float* __restrict__ dinv,
                            float4* __restrict__ xp4, int total4) {
    int idx = blockIdx.x * blockDim.x + threadIdx.x;
    if (idx < total4) {
        float di = dinv[idx >> 4];  // 16 float4 per row
        float4 v = x4[idx];
        v.x *= di; v.y *= di; v.z *= di; v.w *= di;
        xp4[idx] = v;
    }
}

__device__ __forceinline__ float gather_row(const float* __restrict__ xp,
                                            const int* __restrict__ eidx,
                                            int beg, int dcnt, int c, float self) {
    float acc = self;
    for (int base = 0; base < dcnt; base += 64) {
        int j = base + c;
        int ss = (j < dcnt) ? eidx[beg + j] : 0;
        int cnt = min(64, dcnt - base);
        int k = 0;
        for (; k + 4 <= cnt; k += 4) {
            int s0 = __shfl(ss, k, 64), s1 = __shfl(ss, k + 1, 64);
            int s2 = __shfl(ss, k + 2, 64), s3 = __shfl(ss, k + 3, 64);
            float a0 = xp[(long long)s0 * F + c];
            float a1 = xp[(long long)s1 * F + c];
            float a2 = xp[(long long)s2 * F + c];
            float a3 = xp[(long long)s3 * F + c];
            acc += a0; acc += a1; acc += a2; acc += a3;
        }
        for (; k < cnt; k++) {
            int s = __shfl(ss, k, 64);
            acc += xp[(long long)s * F + c];
        }
    }
    return acc;
}

// conv1 fused: t = A_hat x (scaled) ; h1s = ReLU(BN(t@W1+b1)) * dinv
// BN folded into wreg/bias: o = sum t_k*W[k][c]*g' + (b1*g'+beta), g' = gamma*BN_INV
__global__ __launch_bounds__(256) void k_conv1(const float* __restrict__ xp, const int* __restrict__ rowptr,
                                               const int* __restrict__ deg, const int* __restrict__ eidx,
                                               const float* __restrict__ dinv,
                                               const float* __restrict__ W1, const float* __restrict__ b1,
                                               const float* __restrict__ gamma, const float* __restrict__ beta,
                                               float* __restrict__ h1s, int N) {
    __shared__ __align__(16) float tbuf[4][F];
    int tid = threadIdx.x, wave = tid >> 6, c = tid & 63;
    float gs = gamma[c] * BN_INV;
    float bias = fmaf(b1[c], gs, beta[c]);
    float wreg[F];
#pragma unroll
    for (int k = 0; k < F; k++) wreg[k] = W1[k * F + c] * gs;
    float* tb = tbuf[wave];
    for (int i = blockIdx.x * 4 + wave; i < N; i += gridDim.x * 4) {
        float di = dinv[i];
        int beg = rowptr[i], dcnt = deg[i];
        float acc = gather_row(xp, eidx, beg, dcnt, c, xp[(long long)i * F + c]);
        tb[c] = acc * di;  // t[i, c]
        float o = bias;
        const float4* t4 = (const float4*)tb;
#pragma unroll
        for (int k4 = 0; k4 < 16; k4++) {
            float4 tv = t4[k4];  // broadcast read, conflict-free
            o = fmaf(tv.x, wreg[4 * k4 + 0], o);
            o = fmaf(tv.y, wreg[4 * k4 + 1], o);
            o = fmaf(tv.z, wreg[4 * k4 + 2], o);
            o = fmaf(tv.w, wreg[4 * k4 + 3], o);
        }
        h1s[(long long)i * F + c] = fmaxf(o, 0.0f) * di;
    }
}

// conv2 fused: t = A_hat h1 (scaled) ; logits = t@w2l2 + b2l2 ; softmax+entropy -> wraw, min/max
__global__ __launch_bounds__(256) void k_conv2(const float* __restrict__ h1s, const int* __restrict__ rowptr,
                                               const int* __restrict__ deg, const int* __restrict__ eidx,
                                               const float* __restrict__ dinv,
                                               const float* __restrict__ w2l2, const float* __restrict__ b2l2,
                                               float* __restrict__ logits, float* __restrict__ wraw,
                                               unsigned* __restrict__ redmm, int N) {
    __shared__ __align__(16) float tbuf[4][F];
    __shared__ float smn[4], smx[4];
    int tid = threadIdx.x, wave = tid >> 6, c = tid & 63, cc = c & 31;
    float bias = b2l2[cc];
    float wreg[F];
#pragma unroll
    for (int k = 0; k < F; k++) wreg[k] = w2l2[k * OUTF + cc];
    float* tb = tbuf[wave];
    float mn = INFINITY, mx = -INFINITY;
    for (int i = blockIdx.x * 4 + wave; i < N; i += gridDim.x * 4) {
        float di = dinv[i];
        int beg = rowptr[i], dcnt = deg[i];
        float acc = gather_row(h1s, eidx, beg, dcnt, c, h1s[(long long)i * F + c]);
        tb[c] = acc * di;  // t[i, c]
        float o = bias;
        const float4* t4 = (const float4*)tb;
#pragma unroll
        for (int k4 = 0; k4 < 16; k4++) {
            float4 tv = t4[k4];
            o = fmaf(tv.x, wreg[4 * k4 + 0], o);
            o = fmaf(tv.y, wreg[4 * k4 + 1], o);
            o = fmaf(tv.z, wreg[4 * k4 + 2], o);
            o = fmaf(tv.w, wreg[4 * k4 + 3], o);
        }
        // softmax + entropy across 32 lanes (upper half duplicates lower)
        float m = o;
        for (int off = 16; off > 0; off >>= 1) m = fmaxf(m, __shfl_xor(m, off, 32));
        float p = expf(o - m);
        float sum = p;
        for (int off = 16; off > 0; off >>= 1) sum += __shfl_xor(sum, off, 32);
        float t = p / sum;
        float ent = t * logf(t + 1e-9f);
        for (int off = 16; off > 0; off >>= 1) ent += __shfl_xor(ent, off, 32);
        float w = 1.0f / (-ent + 1e-10f);
        if (c < 32) logits[(long long)i * OUTF + c] = o;
        if (c == 0) {
            wraw[i] = w;
            mn = fminf(mn, w);
            mx = fmaxf(mx, w);
        }
    }
    for (int off = 32; off > 0; off >>= 1) {
        mn = fminf(mn, __shfl_xor(mn, off, 64));
        mx = fmaxf(mx, __shfl_xor(mx, off, 64));
    }
    if (c == 0) { smn[wave] = mn; smx[wave] = mx; }
    __syncthreads();
    if (tid == 0) {
        float a = fminf(fminf(smn[0], smn[1]), fminf(smn[2], smn[3]));
        float b = fmaxf(fmaxf(smx[0], smx[1]), fmaxf(smx[2], smx[3]));
        atomicMin(&redmm[33], fenc(a));
        atomicMax(&redmm[34], fenc(b));
    }
}

__global__ __launch_bounds__(256) void k_weight(const float* __restrict__ logits, const float* __restrict__ wraw,
                                                float* __restrict__ red, int N) {
    const unsigned* mm = (const unsigned*)red;
    float mn = fdec(mm[33]), mx = fdec(mm[34]);
    float inv = 1.0f / (mx - mn);
    int c = threadIdx.x & 31;
    int g = threadIdx.x >> 5;  // 8 row-groups
    float acc = 0.0f, es = 0.0f;
    for (int r = blockIdx.x * 8 + g; r < N; r += gridDim.x * 8) {
        float e = expf((wraw[r] - mn) * inv);
        acc += e * logits[(long long)r * OUTF + c];
        if (c == 0) es += e;
    }
    __shared__ float sa[8][OUTF];
    __shared__ float se[8];
    sa[g][c] = acc;
    if (c == 0) se[g] = es;
    __syncthreads();
    if (g == 0) {
        float t = sa[0][c];
#pragma unroll
        for (int i = 1; i < 8; i++) t += sa[i][c];
        unsafeAtomicAdd(&red[c], t);
        if (c == 0) {
            float u = 0.0f;
#pragma unroll
            for (int i = 0; i < 8; i++) u += se[i];
            unsafeAtomicAdd(&red[32], u);
        }
    }
}

__global__ void k_final(const float* __restrict__ red, const float* __restrict__ w3,
                        const float* __restrict__ b3, float* __restrict__ out) {
    int j = threadIdx.x;  // 64 threads
    float s = red[32];
    float o = b3[j];
#pragma unroll
    for (int cc = 0; cc < OUTF; cc++) o += (red[cc] / s) * w3[cc * F + j];
    out[j] = o;
}

extern "C" void kernel_launch(void* const* d_in, const int* in_sizes, int n_in,
                              void* d_out, int out_size, void* d_ws, size_t ws_size,
                              hipStream_t stream) {
    const float* x     = (const float*)d_in[0];
    const int*   ei    = (const int*)d_in[1];
    const float* W1    = (const float*)d_in[2];
    const float* b1    = (const float*)d_in[3];
    const float* gamma = (const float*)d_in[4];
    const float* beta  = (const float*)d_in[5];
    const float* W2    = (const float*)d_in[6];
    const float* b2    = (const float*)d_in[7];
    const float* l2w   = (const float*)d_in[8];
    const float* l2b   = (const float*)d_in[9];
    const float* l3w   = (const float*)d_in[10];
    const float* l3b   = (const float*)d_in[11];

    int N = in_sizes[0] / F;
    int E = in_sizes[1] / 2;
    const int* src = ei;
    const int* dst = ei + E;
    int NB = (N + 255) / 256;

    // workspace layout
    int* deg    = (int*)d_ws;                  // N
    int* rowptr = deg + N;                     // N
    int* cursor = rowptr + N;                  // N
    int* eidx   = cursor + N;                  // E
    float* dinv = (float*)(eidx + E);          // N
    float* red  = dinv + N;                    // 64
    float* w2l2 = red + 64;                    // 2048
    float* b2l2 = w2l2 + F * OUTF;             // 32
    float* h1s  = b2l2 + OUTF;                 // N*64
    float* xp   = h1s + (size_t)N * F;         // N*64 (dead after conv1; aliased below)
    float* logits = xp;                        // N*32
    float* wraw   = xp + (size_t)N * OUTF;     // N

    // CSR build
    k_fuse<<<8, 256, 0, stream>>>(W2, b2, l2w, l2b, w2l2, b2l2, red);
    hipMemsetAsync(deg, 0, (size_t)N * sizeof(int), stream);
    if ((E & 3) == 0) {
        k_deg4<<<(E / 4 + 255) / 256, 256, 0, stream>>>((const int4*)dst, deg, E / 4);
    } else {
        k_deg1<<<(E + 255) / 256, 256, 0, stream>>>(dst, deg, E);
    }
    k_rowptr<<<NB, 256, 0, stream>>>(deg, rowptr, cursor, dinv, (int*)red + 35, N);
    k_prescale4<<<(N * 16 + 255) / 256, 256, 0, stream>>>((const float4*)x, dinv, (float4*)xp, N * 16);
    if ((E & 3) == 0) {
        k_scatter4<<<(E / 4 + 255) / 256, 256, 0, stream>>>((const int4*)src, (const int4*)dst, cursor, eidx, E / 4);
    } else {
        k_scatter1<<<(E + 255) / 256, 256, 0, stream>>>(src, dst, cursor, eidx, E);
    }

    // convs (xp read by conv1; its output h1s read by conv2; logits alias xp)
    k_conv1<<<2048, 256, 0, stream>>>(xp, rowptr, deg, eidx, dinv, W1, b1, gamma, beta, h1s, N);
    k_conv2<<<2048, 256, 0, stream>>>(h1s, rowptr, deg, eidx, dinv, w2l2, b2l2, logits, wraw, (unsigned*)red, N);

    // pooling head
    k_weight<<<1024, 256, 0, stream>>>(logits, wraw, red, N);
    k_final<<<1, 64, 0, stream>>>(red, l3w, l3b, (float*)d_out);
}